// Round 8
// baseline (66.954 us; speedup 1.0000x reference)
//
#include <hip/hip_runtime.h>

// 3D spatial transformer (trilinear grid sample, zeros padding).
// src:  (1,1,160,192,224) f32
// flow: (1,3,160,192,224) f32   channel 0->d, 1->h, 2->w displacement
// out:  (1,1,160,192,224) f32
//
// R8: R5 two-pass structure (pack 2x2x2 bf16 corner table -> 1 gather/voxel)
// with the main kernel restructured for 2x memory-level parallelism:
// 8 voxels/thread, all 8 packed-table gathers issued before any use
// (phase-1 address+issue / phase-2 recompute-weights+consume). R5-main was
// MLP-starved at 0.41 VMEM/cy/CU (R4 proved the CU sustains ~1/cy).

constexpr int Dd = 160;
constexpr int Hh = 192;
constexpr int Ww = 224;
constexpr int HW = Hh * Ww;          // 43008
constexpr int N  = Dd * HW;          // 6,881,280
constexpr int W4 = Ww / 4;           // 56
constexpr int N4 = N / 4;            // 1,720,320
constexpr int NBLK_PACK = N4 / 256;  // 6720
constexpr int W8 = Ww / 8;           // 28
constexpr int N8 = N / 8;            // 860,160
constexpr int NBLK_MAIN = N8 / 128;  // 6720, divisible by 8

typedef float    f32x4 __attribute__((ext_vector_type(4)));
typedef float    f32x2 __attribute__((ext_vector_type(2)));
typedef unsigned u32x4 __attribute__((ext_vector_type(4)));

__device__ __forceinline__ unsigned bf16rne(float x) {
    unsigned u = __builtin_bit_cast(unsigned, x);
    return (u + 0x7fffu + ((u >> 16) & 1u)) >> 16;  // round-nearest-even
}
__device__ __forceinline__ float bflo(unsigned u) {
    return __builtin_bit_cast(float, u << 16);
}
__device__ __forceinline__ float bfhi(unsigned u) {
    return __builtin_bit_cast(float, u & 0xffff0000u);
}

// ---------------- prep: pack 2x2x2 corner patches ----------------
// P[i] (i = (d*Hh+h)*Ww+w), 8 bytes:
//   word0 = bf16(src[d][h][w])    | bf16(src[d][h+1c][w])  <<16   (lo=h, hi=h+1)
//   word1 = bf16(src[d+1c][h][w]) | bf16(src[d+1c][h+1c][w])<<16  (d+1 plane)
__global__ __launch_bounds__(256)
void pack_kernel(const float* __restrict__ src, unsigned* __restrict__ P32) {
    int i4 = blockIdx.x * 256 + threadIdx.x;
    int wq = i4 % W4;
    int t  = i4 / W4;
    int h  = t % Hh;
    int d  = t / Hh;
    int hc = min(h + 1, Hh - 1);
    int dc = min(d + 1, Dd - 1);
    int wo = wq * 4;

    f32x4 a, b, c, e;
    __builtin_memcpy(&a, src + (d  * Hh + h ) * Ww + wo, 16);
    __builtin_memcpy(&b, src + (d  * Hh + hc) * Ww + wo, 16);
    __builtin_memcpy(&c, src + (dc * Hh + h ) * Ww + wo, 16);
    __builtin_memcpy(&e, src + (dc * Hh + hc) * Ww + wo, 16);

    u32x4 q0, q1;
    q0.x = bf16rne(a.x) | (bf16rne(b.x) << 16);
    q0.y = bf16rne(c.x) | (bf16rne(e.x) << 16);
    q0.z = bf16rne(a.y) | (bf16rne(b.y) << 16);
    q0.w = bf16rne(c.y) | (bf16rne(e.y) << 16);
    q1.x = bf16rne(a.z) | (bf16rne(b.z) << 16);
    q1.y = bf16rne(c.z) | (bf16rne(e.z) << 16);
    q1.z = bf16rne(a.w) | (bf16rne(b.w) << 16);
    q1.w = bf16rne(c.w) | (bf16rne(e.w) << 16);

    *((u32x4*)(P32 + (size_t)i4 * 8))     = q0;
    *((u32x4*)(P32 + (size_t)i4 * 8 + 4)) = q1;
}

// ---------------- main: 8 voxels/thread, 1 gather each ----------------
__global__ __launch_bounds__(128)
void st3d_packed_kernel(const unsigned* __restrict__ P32,
                        const float* __restrict__ flow,
                        float* __restrict__ out) {
    // XCD-aware chunked swizzle (6720 % 8 == 0 -> bijective).
    int bid = blockIdx.x;
    int swz = (bid & 7) * (NBLK_MAIN / 8) + (bid >> 3);
    int i8 = swz * 128 + threadIdx.x;

    int w8 = i8 % W8;
    int t  = i8 / W8;
    int h  = t % Hh;
    int d  = t / Hh;
    int gi = i8 * 8;               // == (d*Hh+h)*Ww + w8*8
    int wg = w8 * 8;
    float df = (float)d, hf = (float)h;

    f32x4 fda, fdb, fha, fhb, fwa, fwb;
    __builtin_memcpy(&fda, flow + gi,             16);
    __builtin_memcpy(&fdb, flow + gi + 4,         16);
    __builtin_memcpy(&fha, flow + N + gi,         16);
    __builtin_memcpy(&fhb, flow + N + gi + 4,     16);
    __builtin_memcpy(&fwa, flow + 2 * N + gi,     16);
    __builtin_memcpy(&fwb, flow + 2 * N + gi + 4, 16);

    float fdv[8] = {fda.x, fda.y, fda.z, fda.w, fdb.x, fdb.y, fdb.z, fdb.w};
    float fhv[8] = {fha.x, fha.y, fha.z, fha.w, fhb.x, fhb.y, fhb.z, fhb.w};
    float fwv[8] = {fwa.x, fwa.y, fwa.z, fwa.w, fwb.x, fwb.y, fwb.z, fwb.w};

    // Phase 1: compute all 8 table addresses, issue all 8 gathers.
    u32x4 q[8];
#pragma unroll
    for (int k = 0; k < 8; ++k) {
        float cd = df + fdv[k];
        float ch = hf + fhv[k];
        float cw = (float)(wg + k) + fwv[k];
        int d0 = (int)floorf(cd);
        int h0 = (int)floorf(ch);
        int w0 = (int)floorf(cw);
        int db = min(max(d0, 0), Dd - 1);
        int hb = min(max(h0, 0), Hh - 1);
        int wb = min(max(w0, 0), Ww - 2);
        __builtin_memcpy(&q[k], P32 + (size_t)((db * Hh + hb) * Ww + wb) * 2, 16);
    }

    // Phase 2: recompute weights from register-resident flow, consume q[k].
    float res[8];
#pragma unroll
    for (int k = 0; k < 8; ++k) {
        float cd = df + fdv[k];
        float ch = hf + fhv[k];
        float cw = (float)(wg + k) + fwv[k];

        float d0f = floorf(cd), h0f = floorf(ch), w0f = floorf(cw);
        float fd = cd - d0f, fh = ch - h0f, fw = cw - w0f;
        int d0 = (int)d0f, h0 = (int)h0f, w0 = (int)w0f;

        // Per-axis weights, zeroed out-of-volume (== reference inb mask).
        float wd0 = ((unsigned)d0       < (unsigned)Dd) ? (1.0f - fd) : 0.0f;
        float wd1 = ((unsigned)(d0 + 1) < (unsigned)Dd) ? fd          : 0.0f;
        float wh0 = ((unsigned)h0       < (unsigned)Hh) ? (1.0f - fh) : 0.0f;
        float wh1 = ((unsigned)(h0 + 1) < (unsigned)Hh) ? fh          : 0.0f;
        float ww0 = ((unsigned)w0       < (unsigned)Ww) ? (1.0f - fw) : 0.0f;
        float ww1 = ((unsigned)(w0 + 1) < (unsigned)Ww) ? fw          : 0.0f;

        // Weight-swap for clamped bases (proven exact in R5):
        int wb = min(max(w0, 0), Ww - 2);
        bool sd = d0 < 0;
        bool sh = h0 < 0;
        bool sw = w0 != wb;
        float wdx = sd ? wd1 : wd0, wdy = sd ? wd0 : wd1;
        float whx = sh ? wh1 : wh0, why = sh ? wh0 : wh1;
        float wwx = sw ? ww1 : ww0, wwy = sw ? ww0 : ww1;

        // q[k].x: (h | h+1) @ (d,   wb)    q[k].y: (h | h+1) @ (d+1, wb)
        // q[k].z: (h | h+1) @ (d,   wb+1)  q[k].w: (h | h+1) @ (d+1, wb+1)
        float s0 = wdx * (whx * bflo(q[k].x) + why * bfhi(q[k].x)) +
                   wdy * (whx * bflo(q[k].y) + why * bfhi(q[k].y));
        float s1 = wdx * (whx * bflo(q[k].z) + why * bfhi(q[k].z)) +
                   wdy * (whx * bflo(q[k].w) + why * bfhi(q[k].w));
        res[k] = wwx * s0 + wwy * s1;
    }

    f32x4 r0 = {res[0], res[1], res[2], res[3]};
    f32x4 r1 = {res[4], res[5], res[6], res[7]};
    *(f32x4*)(out + gi)     = r0;
    *(f32x4*)(out + gi + 4) = r1;
}

// ---------------- fallback (R4 kernel) if ws too small ----------------
__device__ __forceinline__ float sample1(const float* __restrict__ src,
                                         float cd, float ch, float cw) {
    float d0f = floorf(cd), h0f = floorf(ch), w0f = floorf(cw);
    float fd = cd - d0f, fh = ch - h0f, fw = cw - w0f;
    int d0 = (int)d0f, h0 = (int)h0f, w0 = (int)w0f;

    float wd0 = ((unsigned)d0       < (unsigned)Dd) ? (1.0f - fd) : 0.0f;
    float wd1 = ((unsigned)(d0 + 1) < (unsigned)Dd) ? fd          : 0.0f;
    float wh0 = ((unsigned)h0       < (unsigned)Hh) ? (1.0f - fh) : 0.0f;
    float wh1 = ((unsigned)(h0 + 1) < (unsigned)Hh) ? fh          : 0.0f;
    float ww0 = ((unsigned)w0       < (unsigned)Ww) ? (1.0f - fw) : 0.0f;
    float ww1 = ((unsigned)(w0 + 1) < (unsigned)Ww) ? fw          : 0.0f;

    int wb = min(max(w0, 0), Ww - 2);
    bool in = (w0 == wb);
    float wx = in ? ww0 : ww1;
    float wy = in ? ww1 : ww0;

    int d0c = min(max(d0, 0), Dd - 1), d1c = min(max(d0 + 1, 0), Dd - 1);
    int h0c = min(max(h0, 0), Hh - 1), h1c = min(max(h0 + 1, 0), Hh - 1);

    f32x2 p00, p01, p10, p11;
    __builtin_memcpy(&p00, src + (d0c * Hh + h0c) * Ww + wb, 8);
    __builtin_memcpy(&p01, src + (d0c * Hh + h1c) * Ww + wb, 8);
    __builtin_memcpy(&p10, src + (d1c * Hh + h0c) * Ww + wb, 8);
    __builtin_memcpy(&p11, src + (d1c * Hh + h1c) * Ww + wb, 8);

    float v00 = wx * p00.x + wy * p00.y;
    float v01 = wx * p01.x + wy * p01.y;
    float v10 = wx * p10.x + wy * p10.y;
    float v11 = wx * p11.x + wy * p11.y;
    return wd0 * (wh0 * v00 + wh1 * v01) + wd1 * (wh0 * v10 + wh1 * v11);
}

__global__ __launch_bounds__(256)
void st3d_kernel(const float* __restrict__ src,
                 const float* __restrict__ flow,
                 float* __restrict__ out) {
    int bid = blockIdx.x;
    int swz = (bid & 7) * (NBLK_PACK / 8) + (bid >> 3);
    int i4 = swz * 256 + threadIdx.x;

    int wq = i4 % W4;
    int t  = i4 / W4;
    int h  = t % Hh;
    int d  = t / Hh;
    float wbf = (float)(wq * 4);
    float df = (float)d, hf = (float)h;

    f32x4 fd4, fh4, fw4;
    __builtin_memcpy(&fd4, (const f32x4*)flow + i4, 16);
    __builtin_memcpy(&fh4, (const f32x4*)(flow + N) + i4, 16);
    __builtin_memcpy(&fw4, (const f32x4*)(flow + 2 * N) + i4, 16);

    f32x4 res;
    res.x = sample1(src, df + fd4.x, hf + fh4.x, wbf + 0.0f + fw4.x);
    res.y = sample1(src, df + fd4.y, hf + fh4.y, wbf + 1.0f + fw4.y);
    res.z = sample1(src, df + fd4.z, hf + fh4.z, wbf + 2.0f + fw4.z);
    res.w = sample1(src, df + fd4.w, hf + fh4.w, wbf + 3.0f + fw4.w);

    *((f32x4*)out + i4) = res;
}

extern "C" void kernel_launch(void* const* d_in, const int* in_sizes, int n_in,
                              void* d_out, int out_size, void* d_ws, size_t ws_size,
                              hipStream_t stream) {
    const float* src  = (const float*)d_in[0];
    const float* flow = (const float*)d_in[1];
    float* out = (float*)d_out;

    if (ws_size >= (size_t)N * 8) {
        unsigned* P32 = (unsigned*)d_ws;
        pack_kernel<<<NBLK_PACK, 256, 0, stream>>>(src, P32);
        st3d_packed_kernel<<<NBLK_MAIN, 128, 0, stream>>>(P32, flow, out);
    } else {
        st3d_kernel<<<NBLK_PACK, 256, 0, stream>>>(src, flow, out);
    }
}

// Round 10
// 65.009 us; speedup vs baseline: 1.0299x; 1.0299x over previous
//
#include <hip/hip_runtime.h>

// 3D spatial transformer (trilinear grid sample, zeros padding).
// src:  (1,1,160,192,224) f32
// flow: (1,3,160,192,224) f32   channel 0->d, 1->h, 2->w displacement
// out:  (1,1,160,192,224) f32
//
// R10: two-pass (pack 2x2x2 bf16 corner table -> one 16B gather/voxel).
// Main kernel: 2 quads/thread (A = base+tid, B = base+tid+256, same
// 2048-voxel span -> R5's proven line-sharing layout) with 8 independent
// VOLATILE table gathers issued before any consume. Volatile forces the
// compiler to issue them in order without sinking (R8 failure: VGPR=32,
// serialized; R9 inline-asm crashed). Model: rate = waves x inflight /
// latency -> 21 x ~14 / 400 ~ 0.8 VMEM/cy/CU vs R5's 0.41.

constexpr int Dd = 160;
constexpr int Hh = 192;
constexpr int Ww = 224;
constexpr int HW = Hh * Ww;          // 43008
constexpr int N  = Dd * HW;          // 6,881,280
constexpr int W4 = Ww / 4;           // 56
constexpr int N4 = N / 4;            // 1,720,320
constexpr int NBLK_PACK = N4 / 256;  // 6720
constexpr int NBLK_MAIN = N4 / 512;  // 3360, divisible by 8

typedef float    f32x4 __attribute__((ext_vector_type(4)));
typedef float    f32x2 __attribute__((ext_vector_type(2)));
typedef unsigned u32x4 __attribute__((ext_vector_type(4)));

__device__ __forceinline__ unsigned bf16rne(float x) {
    unsigned u = __builtin_bit_cast(unsigned, x);
    return (u + 0x7fffu + ((u >> 16) & 1u)) >> 16;  // round-nearest-even
}
__device__ __forceinline__ float bflo(unsigned u) {
    return __builtin_bit_cast(float, u << 16);
}
__device__ __forceinline__ float bfhi(unsigned u) {
    return __builtin_bit_cast(float, u & 0xffff0000u);
}

// ---------------- prep: pack 2x2x2 corner patches (proven in R5) ----------
// P[i] (i = (d*Hh+h)*Ww+w), 8 bytes:
//   word0 = bf16(src[d][h][w])    | bf16(src[d][h+1c][w])  <<16
//   word1 = bf16(src[d+1c][h][w]) | bf16(src[d+1c][h+1c][w])<<16
__global__ __launch_bounds__(256)
void pack_kernel(const float* __restrict__ src, unsigned* __restrict__ P32) {
    int i4 = blockIdx.x * 256 + threadIdx.x;
    int wq = i4 % W4;
    int t  = i4 / W4;
    int h  = t % Hh;
    int d  = t / Hh;
    int hc = min(h + 1, Hh - 1);
    int dc = min(d + 1, Dd - 1);
    int wo = wq * 4;

    f32x4 a, b, c, e;
    __builtin_memcpy(&a, src + (d  * Hh + h ) * Ww + wo, 16);
    __builtin_memcpy(&b, src + (d  * Hh + hc) * Ww + wo, 16);
    __builtin_memcpy(&c, src + (dc * Hh + h ) * Ww + wo, 16);
    __builtin_memcpy(&e, src + (dc * Hh + hc) * Ww + wo, 16);

    u32x4 q0, q1;
    q0.x = bf16rne(a.x) | (bf16rne(b.x) << 16);
    q0.y = bf16rne(c.x) | (bf16rne(e.x) << 16);
    q0.z = bf16rne(a.y) | (bf16rne(b.y) << 16);
    q0.w = bf16rne(c.y) | (bf16rne(e.y) << 16);
    q1.x = bf16rne(a.z) | (bf16rne(b.z) << 16);
    q1.y = bf16rne(c.z) | (bf16rne(e.z) << 16);
    q1.z = bf16rne(a.w) | (bf16rne(b.w) << 16);
    q1.w = bf16rne(c.w) | (bf16rne(e.w) << 16);

    *((u32x4*)(P32 + (size_t)i4 * 8))     = q0;
    *((u32x4*)(P32 + (size_t)i4 * 8 + 4)) = q1;
}

// Per-voxel weight set (post edge-swap, proven exact in R5).
struct WSet { float wdx, wdy, whx, why, wwx, wwy; };

__device__ __forceinline__ WSet make_weights(float cd, float ch, float cw) {
    float d0f = floorf(cd), h0f = floorf(ch), w0f = floorf(cw);
    float fd = cd - d0f, fh = ch - h0f, fw = cw - w0f;
    int d0 = (int)d0f, h0 = (int)h0f, w0 = (int)w0f;

    // Per-axis weights, zeroed out-of-volume (== reference inb mask).
    float wd0 = ((unsigned)d0       < (unsigned)Dd) ? (1.0f - fd) : 0.0f;
    float wd1 = ((unsigned)(d0 + 1) < (unsigned)Dd) ? fd          : 0.0f;
    float wh0 = ((unsigned)h0       < (unsigned)Hh) ? (1.0f - fh) : 0.0f;
    float wh1 = ((unsigned)(h0 + 1) < (unsigned)Hh) ? fh          : 0.0f;
    float ww0 = ((unsigned)w0       < (unsigned)Ww) ? (1.0f - fw) : 0.0f;
    float ww1 = ((unsigned)(w0 + 1) < (unsigned)Ww) ? fw          : 0.0f;

    int wb = min(max(w0, 0), Ww - 2);
    bool sd = d0 < 0;
    bool sh = h0 < 0;
    bool sw = w0 != wb;
    WSet s;
    s.wdx = sd ? wd1 : wd0;  s.wdy = sd ? wd0 : wd1;
    s.whx = sh ? wh1 : wh0;  s.why = sh ? wh0 : wh1;
    s.wwx = sw ? ww1 : ww0;  s.wwy = sw ? ww0 : ww1;
    return s;
}

__device__ __forceinline__ const unsigned* tbl_addr(const unsigned* P32,
                                                    float cd, float ch, float cw) {
    int d0 = (int)floorf(cd);
    int h0 = (int)floorf(ch);
    int w0 = (int)floorf(cw);
    int db = min(max(d0, 0), Dd - 1);
    int hb = min(max(h0, 0), Hh - 1);
    int wb = min(max(w0, 0), Ww - 2);
    return P32 + (size_t)((db * Hh + hb) * Ww + wb) * 2;
}

__device__ __forceinline__ float consume(const u32x4& q, const WSet& s) {
    // q.x: (h|h+1) @ (d,  wb)   q.y: (h|h+1) @ (d+1, wb)
    // q.z: (h|h+1) @ (d,  wb+1) q.w: (h|h+1) @ (d+1, wb+1)
    float s0 = s.wdx * (s.whx * bflo(q.x) + s.why * bfhi(q.x)) +
               s.wdy * (s.whx * bflo(q.y) + s.why * bfhi(q.y));
    float s1 = s.wdx * (s.whx * bflo(q.z) + s.why * bfhi(q.z)) +
               s.wdy * (s.whx * bflo(q.w) + s.why * bfhi(q.w));
    return s.wwx * s0 + s.wwy * s1;
}

// ---------------- main: 2 quads/thread, 8 volatile in-flight gathers -------
__global__ __launch_bounds__(256)
void st3d_packed_kernel(const unsigned* __restrict__ P32,
                        const float* __restrict__ flow,
                        float* __restrict__ out) {
    // XCD-aware chunked swizzle (3360 % 8 == 0 -> bijective).
    int bid = blockIdx.x;
    int swz = (bid & 7) * (NBLK_MAIN / 8) + (bid >> 3);
    int iA = swz * 512 + threadIdx.x;   // quad A (4 voxels)
    int iB = iA + 256;                  // quad B (same 2048-voxel span)

    int wqA = iA % W4, tA = iA / W4, hA = tA % Hh, dA = tA / Hh;
    int wqB = iB % W4, tB = iB / W4, hB = tB % Hh, dB = tB / Hh;
    float wbA = (float)(wqA * 4), dfA = (float)dA, hfA = (float)hA;
    float wbB = (float)(wqB * 4), dfB = (float)dB, hfB = (float)hB;

    // 6 independent coalesced flow loads, issued together.
    f32x4 fdA, fhA, fwA, fdB, fhB, fwB;
    __builtin_memcpy(&fdA, (const f32x4*)flow + iA,           16);
    __builtin_memcpy(&fdB, (const f32x4*)flow + iB,           16);
    __builtin_memcpy(&fhA, (const f32x4*)(flow + N) + iA,     16);
    __builtin_memcpy(&fhB, (const f32x4*)(flow + N) + iB,     16);
    __builtin_memcpy(&fwA, (const f32x4*)(flow + 2 * N) + iA, 16);
    __builtin_memcpy(&fwB, (const f32x4*)(flow + 2 * N) + iB, 16);

    // Coordinates for all 8 voxels.
    float cd0 = dfA + fdA.x, ch0 = hfA + fhA.x, cw0 = wbA + 0.0f + fwA.x;
    float cd1 = dfA + fdA.y, ch1 = hfA + fhA.y, cw1 = wbA + 1.0f + fwA.y;
    float cd2 = dfA + fdA.z, ch2 = hfA + fhA.z, cw2 = wbA + 2.0f + fwA.z;
    float cd3 = dfA + fdA.w, ch3 = hfA + fhA.w, cw3 = wbA + 3.0f + fwA.w;
    float cd4 = dfB + fdB.x, ch4 = hfB + fhB.x, cw4 = wbB + 0.0f + fwB.x;
    float cd5 = dfB + fdB.y, ch5 = hfB + fhB.y, cw5 = wbB + 1.0f + fwB.y;
    float cd6 = dfB + fdB.z, ch6 = hfB + fhB.z, cw6 = wbB + 2.0f + fwB.z;
    float cd7 = dfB + fdB.w, ch7 = hfB + fhB.w, cw7 = wbB + 3.0f + fwB.w;

    // All 8 gathers as volatile 128-bit loads: issued in program order,
    // cannot be sunk/merged -> 8 in flight before first consume.
    const volatile u32x4* g0 = (const volatile u32x4*)tbl_addr(P32, cd0, ch0, cw0);
    const volatile u32x4* g1 = (const volatile u32x4*)tbl_addr(P32, cd1, ch1, cw1);
    const volatile u32x4* g2 = (const volatile u32x4*)tbl_addr(P32, cd2, ch2, cw2);
    const volatile u32x4* g3 = (const volatile u32x4*)tbl_addr(P32, cd3, ch3, cw3);
    const volatile u32x4* g4 = (const volatile u32x4*)tbl_addr(P32, cd4, ch4, cw4);
    const volatile u32x4* g5 = (const volatile u32x4*)tbl_addr(P32, cd5, ch5, cw5);
    const volatile u32x4* g6 = (const volatile u32x4*)tbl_addr(P32, cd6, ch6, cw6);
    const volatile u32x4* g7 = (const volatile u32x4*)tbl_addr(P32, cd7, ch7, cw7);

    u32x4 q0 = *g0;
    u32x4 q1 = *g1;
    u32x4 q2 = *g2;
    u32x4 q3 = *g3;
    u32x4 q4 = *g4;
    u32x4 q5 = *g5;
    u32x4 q6 = *g6;
    u32x4 q7 = *g7;

    // Weights computed in the gather-latency shadow.
    WSet s0 = make_weights(cd0, ch0, cw0);
    WSet s1 = make_weights(cd1, ch1, cw1);
    WSet s2 = make_weights(cd2, ch2, cw2);
    WSet s3 = make_weights(cd3, ch3, cw3);
    WSet s4 = make_weights(cd4, ch4, cw4);
    WSet s5 = make_weights(cd5, ch5, cw5);
    WSet s6 = make_weights(cd6, ch6, cw6);
    WSet s7 = make_weights(cd7, ch7, cw7);

    f32x4 rA, rB;
    rA.x = consume(q0, s0); rA.y = consume(q1, s1);
    rA.z = consume(q2, s2); rA.w = consume(q3, s3);
    rB.x = consume(q4, s4); rB.y = consume(q5, s5);
    rB.z = consume(q6, s6); rB.w = consume(q7, s7);

    *((f32x4*)out + iA) = rA;
    *((f32x4*)out + iB) = rB;
}

// ---------------- fallback (R4 kernel) if ws too small ----------------
__device__ __forceinline__ float sample1(const float* __restrict__ src,
                                         float cd, float ch, float cw) {
    float d0f = floorf(cd), h0f = floorf(ch), w0f = floorf(cw);
    float fd = cd - d0f, fh = ch - h0f, fw = cw - w0f;
    int d0 = (int)d0f, h0 = (int)h0f, w0 = (int)w0f;

    float wd0 = ((unsigned)d0       < (unsigned)Dd) ? (1.0f - fd) : 0.0f;
    float wd1 = ((unsigned)(d0 + 1) < (unsigned)Dd) ? fd          : 0.0f;
    float wh0 = ((unsigned)h0       < (unsigned)Hh) ? (1.0f - fh) : 0.0f;
    float wh1 = ((unsigned)(h0 + 1) < (unsigned)Hh) ? fh          : 0.0f;
    float ww0 = ((unsigned)w0       < (unsigned)Ww) ? (1.0f - fw) : 0.0f;
    float ww1 = ((unsigned)(w0 + 1) < (unsigned)Ww) ? fw          : 0.0f;

    int wb = min(max(w0, 0), Ww - 2);
    bool in = (w0 == wb);
    float wx = in ? ww0 : ww1;
    float wy = in ? ww1 : ww0;

    int d0c = min(max(d0, 0), Dd - 1), d1c = min(max(d0 + 1, 0), Dd - 1);
    int h0c = min(max(h0, 0), Hh - 1), h1c = min(max(h0 + 1, 0), Hh - 1);

    f32x2 p00, p01, p10, p11;
    __builtin_memcpy(&p00, src + (d0c * Hh + h0c) * Ww + wb, 8);
    __builtin_memcpy(&p01, src + (d0c * Hh + h1c) * Ww + wb, 8);
    __builtin_memcpy(&p10, src + (d1c * Hh + h0c) * Ww + wb, 8);
    __builtin_memcpy(&p11, src + (d1c * Hh + h1c) * Ww + wb, 8);

    float v00 = wx * p00.x + wy * p00.y;
    float v01 = wx * p01.x + wy * p01.y;
    float v10 = wx * p10.x + wy * p10.y;
    float v11 = wx * p11.x + wy * p11.y;
    return wd0 * (wh0 * v00 + wh1 * v01) + wd1 * (wh0 * v10 + wh1 * v11);
}

__global__ __launch_bounds__(256)
void st3d_kernel(const float* __restrict__ src,
                 const float* __restrict__ flow,
                 float* __restrict__ out) {
    int bid = blockIdx.x;
    int swz = (bid & 7) * (NBLK_PACK / 8) + (bid >> 3);
    int i4 = swz * 256 + threadIdx.x;

    int wq = i4 % W4;
    int t  = i4 / W4;
    int h  = t % Hh;
    int d  = t / Hh;
    float wbf = (float)(wq * 4);
    float df = (float)d, hf = (float)h;

    f32x4 fd4, fh4, fw4;
    __builtin_memcpy(&fd4, (const f32x4*)flow + i4, 16);
    __builtin_memcpy(&fh4, (const f32x4*)(flow + N) + i4, 16);
    __builtin_memcpy(&fw4, (const f32x4*)(flow + 2 * N) + i4, 16);

    f32x4 res;
    res.x = sample1(src, df + fd4.x, hf + fh4.x, wbf + 0.0f + fw4.x);
    res.y = sample1(src, df + fd4.y, hf + fh4.y, wbf + 1.0f + fw4.y);
    res.z = sample1(src, df + fd4.z, hf + fh4.z, wbf + 2.0f + fw4.z);
    res.w = sample1(src, df + fd4.w, hf + fh4.w, wbf + 3.0f + fw4.w);

    *((f32x4*)out + i4) = res;
}

extern "C" void kernel_launch(void* const* d_in, const int* in_sizes, int n_in,
                              void* d_out, int out_size, void* d_ws, size_t ws_size,
                              hipStream_t stream) {
    const float* src  = (const float*)d_in[0];
    const float* flow = (const float*)d_in[1];
    float* out = (float*)d_out;

    if (ws_size >= (size_t)N * 8) {
        unsigned* P32 = (unsigned*)d_ws;
        pack_kernel<<<NBLK_PACK, 256, 0, stream>>>(src, P32);
        st3d_packed_kernel<<<NBLK_MAIN, 256, 0, stream>>>(P32, flow, out);
    } else {
        st3d_kernel<<<NBLK_PACK, 256, 0, stream>>>(src, flow, out);
    }
}

// Round 11
// 60.883 us; speedup vs baseline: 1.0997x; 1.0678x over previous
//
#include <hip/hip_runtime.h>

// 3D spatial transformer (trilinear grid sample, zeros padding).
// src:  (1,1,160,192,224) f32
// flow: (1,3,160,192,224) f32   channel 0->d, 1->h, 2->w displacement
// out:  (1,1,160,192,224) f32
//
// R11: two-pass (pack 2x2x2 bf16 corner table -> one 16B gather/voxel).
// Main kernel batches 3 tiles/thread: 9 flow loads, then ALL 12 table
// gathers (plain loads), sched_barrier, then consume. The key unlock is
// amdgpu_waves_per_eu(4,4): pins target occupancy at 4 waves/EU so the
// scheduler's VGPR budget is 128 and it stops sinking gathers into the
// consume phase (R8/R10 failure mode: 8-waves/EU target -> <=64 VGPR ->
// serialized gathers). MLP 4 -> ~12 in flight per thread.

constexpr int Dd = 160;
constexpr int Hh = 192;
constexpr int Ww = 224;
constexpr int HW = Hh * Ww;          // 43008
constexpr int N  = Dd * HW;          // 6,881,280
constexpr int W4 = Ww / 4;           // 56
constexpr int N4 = N / 4;            // 1,720,320
constexpr int NBLK_PACK = N4 / 256;  // 6720
constexpr int TILES = 3;
constexpr int QPB = 256 * TILES;     // 768 quads per block (3072 voxels)
constexpr int NBLK_MAIN = N4 / QPB;  // 2240, divisible by 8

typedef float    f32x4 __attribute__((ext_vector_type(4)));
typedef float    f32x2 __attribute__((ext_vector_type(2)));
typedef unsigned u32x4 __attribute__((ext_vector_type(4)));

__device__ __forceinline__ unsigned bf16rne(float x) {
    unsigned u = __builtin_bit_cast(unsigned, x);
    return (u + 0x7fffu + ((u >> 16) & 1u)) >> 16;  // round-nearest-even
}
__device__ __forceinline__ float bflo(unsigned u) {
    return __builtin_bit_cast(float, u << 16);
}
__device__ __forceinline__ float bfhi(unsigned u) {
    return __builtin_bit_cast(float, u & 0xffff0000u);
}

// ---------------- prep: pack 2x2x2 corner patches (proven in R5) ----------
// P[i] (i = (d*Hh+h)*Ww+w), 8 bytes:
//   word0 = bf16(src[d][h][w])    | bf16(src[d][h+1c][w])  <<16
//   word1 = bf16(src[d+1c][h][w]) | bf16(src[d+1c][h+1c][w])<<16
__global__ __launch_bounds__(256)
void pack_kernel(const float* __restrict__ src, unsigned* __restrict__ P32) {
    int i4 = blockIdx.x * 256 + threadIdx.x;
    int wq = i4 % W4;
    int t  = i4 / W4;
    int h  = t % Hh;
    int d  = t / Hh;
    int hc = min(h + 1, Hh - 1);
    int dc = min(d + 1, Dd - 1);
    int wo = wq * 4;

    f32x4 a, b, c, e;
    __builtin_memcpy(&a, src + (d  * Hh + h ) * Ww + wo, 16);
    __builtin_memcpy(&b, src + (d  * Hh + hc) * Ww + wo, 16);
    __builtin_memcpy(&c, src + (dc * Hh + h ) * Ww + wo, 16);
    __builtin_memcpy(&e, src + (dc * Hh + hc) * Ww + wo, 16);

    u32x4 q0, q1;
    q0.x = bf16rne(a.x) | (bf16rne(b.x) << 16);
    q0.y = bf16rne(c.x) | (bf16rne(e.x) << 16);
    q0.z = bf16rne(a.y) | (bf16rne(b.y) << 16);
    q0.w = bf16rne(c.y) | (bf16rne(e.y) << 16);
    q1.x = bf16rne(a.z) | (bf16rne(b.z) << 16);
    q1.y = bf16rne(c.z) | (bf16rne(e.z) << 16);
    q1.z = bf16rne(a.w) | (bf16rne(b.w) << 16);
    q1.w = bf16rne(c.w) | (bf16rne(e.w) << 16);

    *((u32x4*)(P32 + (size_t)i4 * 8))     = q0;
    *((u32x4*)(P32 + (size_t)i4 * 8 + 4)) = q1;
}

// Per-voxel weight set (post edge-swap, proven exact in R5).
struct WSet { float wdx, wdy, whx, why, wwx, wwy; };

__device__ __forceinline__ WSet make_weights(float cd, float ch, float cw) {
    float d0f = floorf(cd), h0f = floorf(ch), w0f = floorf(cw);
    float fd = cd - d0f, fh = ch - h0f, fw = cw - w0f;
    int d0 = (int)d0f, h0 = (int)h0f, w0 = (int)w0f;

    // Per-axis weights, zeroed out-of-volume (== reference inb mask).
    float wd0 = ((unsigned)d0       < (unsigned)Dd) ? (1.0f - fd) : 0.0f;
    float wd1 = ((unsigned)(d0 + 1) < (unsigned)Dd) ? fd          : 0.0f;
    float wh0 = ((unsigned)h0       < (unsigned)Hh) ? (1.0f - fh) : 0.0f;
    float wh1 = ((unsigned)(h0 + 1) < (unsigned)Hh) ? fh          : 0.0f;
    float ww0 = ((unsigned)w0       < (unsigned)Ww) ? (1.0f - fw) : 0.0f;
    float ww1 = ((unsigned)(w0 + 1) < (unsigned)Ww) ? fw          : 0.0f;

    int wb = min(max(w0, 0), Ww - 2);
    bool sd = d0 < 0;
    bool sh = h0 < 0;
    bool sw = w0 != wb;
    WSet s;
    s.wdx = sd ? wd1 : wd0;  s.wdy = sd ? wd0 : wd1;
    s.whx = sh ? wh1 : wh0;  s.why = sh ? wh0 : wh1;
    s.wwx = sw ? ww1 : ww0;  s.wwy = sw ? ww0 : ww1;
    return s;
}

__device__ __forceinline__ const unsigned* tbl_addr(const unsigned* P32,
                                                    float cd, float ch, float cw) {
    int d0 = (int)floorf(cd);
    int h0 = (int)floorf(ch);
    int w0 = (int)floorf(cw);
    int db = min(max(d0, 0), Dd - 1);
    int hb = min(max(h0, 0), Hh - 1);
    int wb = min(max(w0, 0), Ww - 2);
    return P32 + (size_t)((db * Hh + hb) * Ww + wb) * 2;
}

__device__ __forceinline__ float consume(const u32x4& q, const WSet& s) {
    // q.x: (h|h+1) @ (d,  wb)   q.y: (h|h+1) @ (d+1, wb)
    // q.z: (h|h+1) @ (d,  wb+1) q.w: (h|h+1) @ (d+1, wb+1)
    float s0 = s.wdx * (s.whx * bflo(q.x) + s.why * bfhi(q.x)) +
               s.wdy * (s.whx * bflo(q.y) + s.why * bfhi(q.y));
    float s1 = s.wdx * (s.whx * bflo(q.z) + s.why * bfhi(q.z)) +
               s.wdy * (s.whx * bflo(q.w) + s.why * bfhi(q.w));
    return s.wwx * s0 + s.wwy * s1;
}

// ---------------- main: 3 tiles/thread, 12 batched gathers ----------------
__global__ __attribute__((amdgpu_waves_per_eu(4, 4))) __launch_bounds__(256)
void st3d_packed_kernel(const unsigned* __restrict__ P32,
                        const float* __restrict__ flow,
                        float* __restrict__ out) {
    // XCD-aware chunked swizzle (2240 % 8 == 0 -> bijective).
    int bid = blockIdx.x;
    int swz = (bid & 7) * (NBLK_MAIN / 8) + (bid >> 3);
    int base = swz * QPB + threadIdx.x;

    // Phase 1: 9 independent coalesced flow loads.
    f32x4 fd[TILES], fh[TILES], fw[TILES];
#pragma unroll
    for (int t = 0; t < TILES; ++t) {
        int i4 = base + t * 256;
        __builtin_memcpy(&fd[t], (const f32x4*)flow + i4,           16);
        __builtin_memcpy(&fh[t], (const f32x4*)(flow + N) + i4,     16);
        __builtin_memcpy(&fw[t], (const f32x4*)(flow + 2 * N) + i4, 16);
    }

    // Per-tile geometry (kept in registers for the consume phase).
    float wbf[TILES], dff[TILES], hff[TILES];
#pragma unroll
    for (int t = 0; t < TILES; ++t) {
        int i4 = base + t * 256;
        int wq = i4 % W4;
        int tt = i4 / W4;
        wbf[t] = (float)(wq * 4);
        hff[t] = (float)(tt % Hh);
        dff[t] = (float)(tt / Hh);
    }

    // Phase 2: ALL 12 table gathers issued before any consume.
    u32x4 q[TILES][4];
#pragma unroll
    for (int t = 0; t < TILES; ++t) {
#pragma unroll
        for (int k = 0; k < 4; ++k) {
            float cd = dff[t] + fd[t][k];
            float ch = hff[t] + fh[t][k];
            float cw = wbf[t] + (float)k + fw[t][k];
            __builtin_memcpy(&q[t][k], tbl_addr(P32, cd, ch, cw), 16);
        }
    }
    __builtin_amdgcn_sched_barrier(0);   // pin: no consume above the gathers

    // Phase 3: weights recomputed from register-resident flow; consume; store.
#pragma unroll
    for (int t = 0; t < TILES; ++t) {
        f32x4 r;
#pragma unroll
        for (int k = 0; k < 4; ++k) {
            float cd = dff[t] + fd[t][k];
            float ch = hff[t] + fh[t][k];
            float cw = wbf[t] + (float)k + fw[t][k];
            WSet s = make_weights(cd, ch, cw);
            r[k] = consume(q[t][k], s);
        }
        *((f32x4*)out + (base + t * 256)) = r;
    }
}

// ---------------- fallback (R4 kernel) if ws too small ----------------
__device__ __forceinline__ float sample1(const float* __restrict__ src,
                                         float cd, float ch, float cw) {
    float d0f = floorf(cd), h0f = floorf(ch), w0f = floorf(cw);
    float fd = cd - d0f, fh = ch - h0f, fw = cw - w0f;
    int d0 = (int)d0f, h0 = (int)h0f, w0 = (int)w0f;

    float wd0 = ((unsigned)d0       < (unsigned)Dd) ? (1.0f - fd) : 0.0f;
    float wd1 = ((unsigned)(d0 + 1) < (unsigned)Dd) ? fd          : 0.0f;
    float wh0 = ((unsigned)h0       < (unsigned)Hh) ? (1.0f - fh) : 0.0f;
    float wh1 = ((unsigned)(h0 + 1) < (unsigned)Hh) ? fh          : 0.0f;
    float ww0 = ((unsigned)w0       < (unsigned)Ww) ? (1.0f - fw) : 0.0f;
    float ww1 = ((unsigned)(w0 + 1) < (unsigned)Ww) ? fw          : 0.0f;

    int wb = min(max(w0, 0), Ww - 2);
    bool in = (w0 == wb);
    float wx = in ? ww0 : ww1;
    float wy = in ? ww1 : ww0;

    int d0c = min(max(d0, 0), Dd - 1), d1c = min(max(d0 + 1, 0), Dd - 1);
    int h0c = min(max(h0, 0), Hh - 1), h1c = min(max(h0 + 1, 0), Hh - 1);

    f32x2 p00, p01, p10, p11;
    __builtin_memcpy(&p00, src + (d0c * Hh + h0c) * Ww + wb, 8);
    __builtin_memcpy(&p01, src + (d0c * Hh + h1c) * Ww + wb, 8);
    __builtin_memcpy(&p10, src + (d1c * Hh + h0c) * Ww + wb, 8);
    __builtin_memcpy(&p11, src + (d1c * Hh + h1c) * Ww + wb, 8);

    float v00 = wx * p00.x + wy * p00.y;
    float v01 = wx * p01.x + wy * p01.y;
    float v10 = wx * p10.x + wy * p10.y;
    float v11 = wx * p11.x + wy * p11.y;
    return wd0 * (wh0 * v00 + wh1 * v01) + wd1 * (wh0 * v10 + wh1 * v11);
}

__global__ __launch_bounds__(256)
void st3d_kernel(const float* __restrict__ src,
                 const float* __restrict__ flow,
                 float* __restrict__ out) {
    int bid = blockIdx.x;
    int swz = (bid & 7) * (NBLK_PACK / 8) + (bid >> 3);
    int i4 = swz * 256 + threadIdx.x;

    int wq = i4 % W4;
    int t  = i4 / W4;
    int h  = t % Hh;
    int d  = t / Hh;
    float wbf = (float)(wq * 4);
    float df = (float)d, hf = (float)h;

    f32x4 fd4, fh4, fw4;
    __builtin_memcpy(&fd4, (const f32x4*)flow + i4, 16);
    __builtin_memcpy(&fh4, (const f32x4*)(flow + N) + i4, 16);
    __builtin_memcpy(&fw4, (const f32x4*)(flow + 2 * N) + i4, 16);

    f32x4 res;
    res.x = sample1(src, df + fd4.x, hf + fh4.x, wbf + 0.0f + fw4.x);
    res.y = sample1(src, df + fd4.y, hf + fh4.y, wbf + 1.0f + fw4.y);
    res.z = sample1(src, df + fd4.z, hf + fh4.z, wbf + 2.0f + fw4.z);
    res.w = sample1(src, df + fd4.w, hf + fh4.w, wbf + 3.0f + fw4.w);

    *((f32x4*)out + i4) = res;
}

extern "C" void kernel_launch(void* const* d_in, const int* in_sizes, int n_in,
                              void* d_out, int out_size, void* d_ws, size_t ws_size,
                              hipStream_t stream) {
    const float* src  = (const float*)d_in[0];
    const float* flow = (const float*)d_in[1];
    float* out = (float*)d_out;

    if (ws_size >= (size_t)N * 8) {
        unsigned* P32 = (unsigned*)d_ws;
        pack_kernel<<<NBLK_PACK, 256, 0, stream>>>(src, P32);
        st3d_packed_kernel<<<NBLK_MAIN, 256, 0, stream>>>(P32, flow, out);
    } else {
        st3d_kernel<<<NBLK_PACK, 256, 0, stream>>>(src, flow, out);
    }
}

// Round 12
// 56.664 us; speedup vs baseline: 1.1816x; 1.0745x over previous
//
#include <hip/hip_runtime.h>

// 3D spatial transformer (trilinear grid sample, zeros padding).
// src:  (1,1,160,192,224) f32
// flow: (1,3,160,192,224) f32   channel 0->d, 1->h, 2->w displacement
// out:  (1,1,160,192,224) f32
//
// R12 = revert to R5 (best measured: 56.9us), which sits at the modeled
// structural floor for this op on MI355X:
//   cost ~ 4cy per distinct L1-missing line per CU.
//   main: ~1 line/voxel (per-voxel flow jitter defeats line sharing for any
//         layout) -> 6.88M lines x 4cy / 256 CU ~ 45us
//   pack: BW-bound, 83MB @ ~6.3TB/s ~ 13us
// Verified: R4 (no table, 1.25 lines/voxel) ~ 57.7; R5 ~ 56.9; every LDS
// (R6/R7) and MLP-forcing (R8-R11) variant landed above both.
//
// Structure: pass 1 packs the 2x2x2 corner patch of every voxel into 8B
// (4 x bf16); pass 2 does ONE 16B gather per voxel (covers w0,w0+1) and
// blends with per-axis weights. Out-of-volume corner weights are zeroed
// (== reference's inb mask), and clamped bases use the weight-swap trick,
// so clamp-staged values are never actually used.

constexpr int Dd = 160;
constexpr int Hh = 192;
constexpr int Ww = 224;
constexpr int HW = Hh * Ww;          // 43008
constexpr int N  = Dd * HW;          // 6,881,280
constexpr int W4 = Ww / 4;           // 56
constexpr int N4 = N / 4;            // 1,720,320
constexpr int NBLK = N4 / 256;       // 6720, divisible by 8

typedef float    f32x4 __attribute__((ext_vector_type(4)));
typedef float    f32x2 __attribute__((ext_vector_type(2)));
typedef unsigned u32x4 __attribute__((ext_vector_type(4)));

__device__ __forceinline__ unsigned bf16rne(float x) {
    unsigned u = __builtin_bit_cast(unsigned, x);
    return (u + 0x7fffu + ((u >> 16) & 1u)) >> 16;  // round-nearest-even
}
__device__ __forceinline__ float bflo(unsigned u) {  // low bf16 -> f32
    return __builtin_bit_cast(float, u << 16);
}
__device__ __forceinline__ float bfhi(unsigned u) {  // high bf16 -> f32
    return __builtin_bit_cast(float, u & 0xffff0000u);
}

// ---------------- prep: pack 2x2x2 corner patches ----------------
// P[i] (i = (d*Hh+h)*Ww+w), 8 bytes:
//   word0 = bf16(src[d][h][w])    | bf16(src[d][h+1c][w])  <<16
//   word1 = bf16(src[d+1c][h][w]) | bf16(src[d+1c][h+1c][w])<<16
__global__ __launch_bounds__(256)
void pack_kernel(const float* __restrict__ src, unsigned* __restrict__ P32) {
    int i4 = blockIdx.x * 256 + threadIdx.x;
    int wq = i4 % W4;
    int t  = i4 / W4;
    int h  = t % Hh;
    int d  = t / Hh;
    int hc = min(h + 1, Hh - 1);
    int dc = min(d + 1, Dd - 1);
    int wo = wq * 4;

    f32x4 a, b, c, e;
    __builtin_memcpy(&a, src + (d  * Hh + h ) * Ww + wo, 16);
    __builtin_memcpy(&b, src + (d  * Hh + hc) * Ww + wo, 16);
    __builtin_memcpy(&c, src + (dc * Hh + h ) * Ww + wo, 16);
    __builtin_memcpy(&e, src + (dc * Hh + hc) * Ww + wo, 16);

    u32x4 q0, q1;
    q0.x = bf16rne(a.x) | (bf16rne(b.x) << 16);
    q0.y = bf16rne(c.x) | (bf16rne(e.x) << 16);
    q0.z = bf16rne(a.y) | (bf16rne(b.y) << 16);
    q0.w = bf16rne(c.y) | (bf16rne(e.y) << 16);
    q1.x = bf16rne(a.z) | (bf16rne(b.z) << 16);
    q1.y = bf16rne(c.z) | (bf16rne(e.z) << 16);
    q1.z = bf16rne(a.w) | (bf16rne(b.w) << 16);
    q1.w = bf16rne(c.w) | (bf16rne(e.w) << 16);

    *((u32x4*)(P32 + (size_t)i4 * 8))     = q0;
    *((u32x4*)(P32 + (size_t)i4 * 8 + 4)) = q1;
}

// ---------------- main: one 16B gather per voxel ----------------
__device__ __forceinline__ float sample_packed(const unsigned* __restrict__ P32,
                                               float cd, float ch, float cw) {
    float d0f = floorf(cd), h0f = floorf(ch), w0f = floorf(cw);
    float fd = cd - d0f, fh = ch - h0f, fw = cw - w0f;
    int d0 = (int)d0f, h0 = (int)h0f, w0 = (int)w0f;

    // Per-axis weights, zeroed when that coordinate is out of bounds
    // (product == reference's wd*wh*ww*inb).
    float wd0 = ((unsigned)d0       < (unsigned)Dd) ? (1.0f - fd) : 0.0f;
    float wd1 = ((unsigned)(d0 + 1) < (unsigned)Dd) ? fd          : 0.0f;
    float wh0 = ((unsigned)h0       < (unsigned)Hh) ? (1.0f - fh) : 0.0f;
    float wh1 = ((unsigned)(h0 + 1) < (unsigned)Hh) ? fh          : 0.0f;
    float ww0 = ((unsigned)w0       < (unsigned)Ww) ? (1.0f - fw) : 0.0f;
    float ww1 = ((unsigned)(w0 + 1) < (unsigned)Ww) ? fw          : 0.0f;

    // Clamped bases; swap the weight pair when the base clamped up from
    // below (the needed value then sits in the other slot, and the OOB
    // slot's weight is already 0). For w, clamping to Ww-2 at the top edge
    // also swaps (w0=223 -> pair=[222,223], need ww0 on .y).
    int db = min(max(d0, 0), Dd - 1);
    int hb = min(max(h0, 0), Hh - 1);
    int wb = min(max(w0, 0), Ww - 2);
    bool sd = d0 < 0;
    bool sh = h0 < 0;
    bool sw = w0 != wb;

    float wdx = sd ? wd1 : wd0, wdy = sd ? wd0 : wd1;
    float whx = sh ? wh1 : wh0, why = sh ? wh0 : wh1;
    float wwx = sw ? ww1 : ww0, wwy = sw ? ww0 : ww1;

    u32x4 q;
    __builtin_memcpy(&q, P32 + (size_t)((db * Hh + hb) * Ww + wb) * 2, 16);

    // q.x: (h|h+1) @ (d,  wb)    q.y: (h|h+1) @ (d+1, wb)
    // q.z: (h|h+1) @ (d,  wb+1)  q.w: (h|h+1) @ (d+1, wb+1)
    float s0 = wdx * (whx * bflo(q.x) + why * bfhi(q.x)) +
               wdy * (whx * bflo(q.y) + why * bfhi(q.y));
    float s1 = wdx * (whx * bflo(q.z) + why * bfhi(q.z)) +
               wdy * (whx * bflo(q.w) + why * bfhi(q.w));
    return wwx * s0 + wwy * s1;
}

__global__ __launch_bounds__(256)
void st3d_packed_kernel(const unsigned* __restrict__ P32,
                        const float* __restrict__ flow,
                        float* __restrict__ out) {
    // XCD-aware chunked swizzle (6720 % 8 == 0 -> bijective): each XCD gets
    // 840 consecutive blocks = a contiguous ~20-d-slice slab (P slab ~6.9MB
    // -> L2+L3 resident).
    int bid = blockIdx.x;
    int swz = (bid & 7) * (NBLK / 8) + (bid >> 3);
    int i4 = swz * 256 + threadIdx.x;

    int wq = i4 % W4;
    int t  = i4 / W4;
    int h  = t % Hh;
    int d  = t / Hh;
    float wbf = (float)(wq * 4);
    float df = (float)d, hf = (float)h;

    f32x4 fd4, fh4, fw4;
    __builtin_memcpy(&fd4, (const f32x4*)flow + i4, 16);
    __builtin_memcpy(&fh4, (const f32x4*)(flow + N) + i4, 16);
    __builtin_memcpy(&fw4, (const f32x4*)(flow + 2 * N) + i4, 16);

    f32x4 res;
    res.x = sample_packed(P32, df + fd4.x, hf + fh4.x, wbf + 0.0f + fw4.x);
    res.y = sample_packed(P32, df + fd4.y, hf + fh4.y, wbf + 1.0f + fw4.y);
    res.z = sample_packed(P32, df + fd4.z, hf + fh4.z, wbf + 2.0f + fw4.z);
    res.w = sample_packed(P32, df + fd4.w, hf + fh4.w, wbf + 3.0f + fw4.w);

    *((f32x4*)out + i4) = res;
}

// ---------------- fallback (R4 kernel) if ws too small ----------------
__device__ __forceinline__ float sample1(const float* __restrict__ src,
                                         float cd, float ch, float cw) {
    float d0f = floorf(cd), h0f = floorf(ch), w0f = floorf(cw);
    float fd = cd - d0f, fh = ch - h0f, fw = cw - w0f;
    int d0 = (int)d0f, h0 = (int)h0f, w0 = (int)w0f;

    float wd0 = ((unsigned)d0       < (unsigned)Dd) ? (1.0f - fd) : 0.0f;
    float wd1 = ((unsigned)(d0 + 1) < (unsigned)Dd) ? fd          : 0.0f;
    float wh0 = ((unsigned)h0       < (unsigned)Hh) ? (1.0f - fh) : 0.0f;
    float wh1 = ((unsigned)(h0 + 1) < (unsigned)Hh) ? fh          : 0.0f;
    float ww0 = ((unsigned)w0       < (unsigned)Ww) ? (1.0f - fw) : 0.0f;
    float ww1 = ((unsigned)(w0 + 1) < (unsigned)Ww) ? fw          : 0.0f;

    int wb = min(max(w0, 0), Ww - 2);
    bool in = (w0 == wb);
    float wx = in ? ww0 : ww1;
    float wy = in ? ww1 : ww0;

    int d0c = min(max(d0, 0), Dd - 1), d1c = min(max(d0 + 1, 0), Dd - 1);
    int h0c = min(max(h0, 0), Hh - 1), h1c = min(max(h0 + 1, 0), Hh - 1);

    f32x2 p00, p01, p10, p11;
    __builtin_memcpy(&p00, src + (d0c * Hh + h0c) * Ww + wb, 8);
    __builtin_memcpy(&p01, src + (d0c * Hh + h1c) * Ww + wb, 8);
    __builtin_memcpy(&p10, src + (d1c * Hh + h0c) * Ww + wb, 8);
    __builtin_memcpy(&p11, src + (d1c * Hh + h1c) * Ww + wb, 8);

    float v00 = wx * p00.x + wy * p00.y;
    float v01 = wx * p01.x + wy * p01.y;
    float v10 = wx * p10.x + wy * p10.y;
    float v11 = wx * p11.x + wy * p11.y;
    return wd0 * (wh0 * v00 + wh1 * v01) + wd1 * (wh0 * v10 + wh1 * v11);
}

__global__ __launch_bounds__(256)
void st3d_kernel(const float* __restrict__ src,
                 const float* __restrict__ flow,
                 float* __restrict__ out) {
    int bid = blockIdx.x;
    int swz = (bid & 7) * (NBLK / 8) + (bid >> 3);
    int i4 = swz * 256 + threadIdx.x;

    int wq = i4 % W4;
    int t  = i4 / W4;
    int h  = t % Hh;
    int d  = t / Hh;
    float wbf = (float)(wq * 4);
    float df = (float)d, hf = (float)h;

    f32x4 fd4, fh4, fw4;
    __builtin_memcpy(&fd4, (const f32x4*)flow + i4, 16);
    __builtin_memcpy(&fh4, (const f32x4*)(flow + N) + i4, 16);
    __builtin_memcpy(&fw4, (const f32x4*)(flow + 2 * N) + i4, 16);

    f32x4 res;
    res.x = sample1(src, df + fd4.x, hf + fh4.x, wbf + 0.0f + fw4.x);
    res.y = sample1(src, df + fd4.y, hf + fh4.y, wbf + 1.0f + fw4.y);
    res.z = sample1(src, df + fd4.z, hf + fh4.z, wbf + 2.0f + fw4.z);
    res.w = sample1(src, df + fd4.w, hf + fh4.w, wbf + 3.0f + fw4.w);

    *((f32x4*)out + i4) = res;
}

extern "C" void kernel_launch(void* const* d_in, const int* in_sizes, int n_in,
                              void* d_out, int out_size, void* d_ws, size_t ws_size,
                              hipStream_t stream) {
    const float* src  = (const float*)d_in[0];
    const float* flow = (const float*)d_in[1];
    float* out = (float*)d_out;

    if (ws_size >= (size_t)N * 8) {
        unsigned* P32 = (unsigned*)d_ws;
        pack_kernel<<<NBLK, 256, 0, stream>>>(src, P32);
        st3d_packed_kernel<<<NBLK, 256, 0, stream>>>(P32, flow, out);
    } else {
        st3d_kernel<<<NBLK, 256, 0, stream>>>(src, flow, out);
    }
}